// Round 1
// baseline (383.302 us; speedup 1.0000x reference)
//
#include <hip/hip_runtime.h>
#include <hip/hip_bf16.h>

#define S 2048
#define DM 2048
#define NH 16
#define DH 128

typedef __attribute__((ext_vector_type(8))) short short8;
typedef __attribute__((ext_vector_type(4))) float floatx4;
typedef unsigned short u16;
typedef unsigned int u32;

__device__ __forceinline__ u16 f2bf(float f) {
  union { float f; u32 u; } v; v.f = f;
  u32 r = v.u + 0x7fffu + ((v.u >> 16) & 1u);
  return (u16)(r >> 16);
}
// HW packed round-to-nearest-even f32x2 -> bf16x2 (v_cvt_pk_bf16_f32)
__device__ __forceinline__ u32 pack2(float lo, float hi) {
  float2 f; f.x = lo; f.y = hi;
  __hip_bfloat162 h = __float22bfloat162_rn(f);
  union { __hip_bfloat162 h; u32 u; } c; c.h = h;
  return c.u;
}

__device__ __forceinline__ floatx4 mfma16(short8 a, short8 b, floatx4 c) {
  return __builtin_amdgcn_mfma_f32_16x16x32_bf16(a, b, c, 0, 0, 0);
}

// async global -> LDS, 16B per lane. LDS dest = wave-uniform base + lane*16.
__device__ __forceinline__ void async_cp16(const u16* g, u16* l) {
  __builtin_amdgcn_global_load_lds(
      (const __attribute__((address_space(1))) void*)g,
      (__attribute__((address_space(3))) void*)l, 16, 0, 0);
}

// ---------- convert x (fp32 -> bf16), 4 elems/thread ----------
__global__ void conv_x_k(const float* __restrict__ x, u16* __restrict__ xb) {
  int gid = blockIdx.x * 256 + threadIdx.x;
  float4 v = ((const float4*)x)[gid];
  uint2 p; p.x = pack2(v.x, v.y); p.y = pack2(v.z, v.w);
  ((uint2*)xb)[gid] = p;
}

// ---------- transpose+convert weights: Wt[n*2048+k] = bf16(W[k*2048+n]) ----------
__global__ void conv_w_k(const float* __restrict__ W0, const float* __restrict__ W1,
                         const float* __restrict__ W2, const float* __restrict__ W3,
                         u16* __restrict__ out) {
  __shared__ float tile[32][33];
  const float* W = blockIdx.z == 0 ? W0 : blockIdx.z == 1 ? W1 : blockIdx.z == 2 ? W2 : W3;
  u16* O = out + (size_t)blockIdx.z * DM * DM;
  int tx = threadIdx.x & 31, ty = threadIdx.x >> 5;
  int k0 = blockIdx.y * 32, n0 = blockIdx.x * 32;
#pragma unroll
  for (int j = 0; j < 4; j++)
    tile[ty + j * 8][tx] = W[(size_t)(k0 + ty + j * 8) * DM + n0 + tx];
  __syncthreads();
#pragma unroll
  for (int j = 0; j < 4; j++)
    O[(size_t)(n0 + ty + j * 8) * DM + k0 + tx] = f2bf(tile[tx][ty + j * 8]);
}

// ---------- 256x128 bf16 MFMA GEMM, 8-phase schedule (T2+T3+T4+T5) ----------
// 8 waves (2M x 4N), BK=64, double-buffered LDS (96 KiB), counted vmcnt(6):
// per iteration 2 K-tiles x 4 phases of {ds_read -> bar -> lgkm0 -> setprio ->
// 8 MFMA -> bar}; tile T+2 staged into the just-freed buffer at each half-
// iteration boundary. vmcnt never drains to 0 in steady state.
// LDS swizzle: granule g' = g ^ (row&7) (involution), linear global_load_lds
// dest + inverse-swizzled global src + swizzled ds_read (rule #21).
#define BM 256
#define BN 128
#define BK 64
#define NT (DM / BK)   // 32 K-tiles, 16 iterations

#define STAGE(p, koff) do {                       \
    async_cp16(pA0 + (koff), &As[p][oA0]);        \
    async_cp16(pA1 + (koff), &As[p][oA1]);        \
    async_cp16(pA2 + (koff), &As[p][oA2]);        \
    async_cp16(pA3 + (koff), &As[p][oA3]);        \
    async_cp16(pB0 + (koff), &Bs[p][oB0]);        \
    async_cp16(pB1 + (koff), &Bs[p][oB1]);        \
  } while (0)

#define PHASE(p, g, F) {                                                  \
    short8 a0k0 = *(const short8*)&As[p][arow64 + (2*(g))*1024 + xk0];    \
    short8 a0k1 = *(const short8*)&As[p][arow64 + (2*(g))*1024 + xk1];    \
    short8 a1k0 = *(const short8*)&As[p][arow64 + (2*(g)+1)*1024 + xk0];  \
    short8 a1k1 = *(const short8*)&As[p][arow64 + (2*(g)+1)*1024 + xk1];  \
    if (F) {                                                              \
      bA = *(const short8*)&Bs[p][brow64 + xk0];                          \
      bB = *(const short8*)&Bs[p][brow64 + xk1];                          \
      bC = *(const short8*)&Bs[p][brow64 + 1024 + xk0];                   \
      bD = *(const short8*)&Bs[p][brow64 + 1024 + xk1];                   \
    }                                                                     \
    __builtin_amdgcn_s_barrier();                                         \
    asm volatile("s_waitcnt lgkmcnt(0)" ::: "memory");                    \
    __builtin_amdgcn_sched_barrier(0);                                    \
    __builtin_amdgcn_s_setprio(1);                                        \
    acc[2*(g)][0]   = mfma16(a0k0, bA, acc[2*(g)][0]);                    \
    acc[2*(g)][1]   = mfma16(a0k0, bC, acc[2*(g)][1]);                    \
    acc[2*(g)+1][0] = mfma16(a1k0, bA, acc[2*(g)+1][0]);                  \
    acc[2*(g)+1][1] = mfma16(a1k0, bC, acc[2*(g)+1][1]);                  \
    acc[2*(g)][0]   = mfma16(a0k1, bB, acc[2*(g)][0]);                    \
    acc[2*(g)][1]   = mfma16(a0k1, bD, acc[2*(g)][1]);                    \
    acc[2*(g)+1][0] = mfma16(a1k1, bB, acc[2*(g)+1][0]);                  \
    acc[2*(g)+1][1] = mfma16(a1k1, bD, acc[2*(g)+1][1]);                  \
    __builtin_amdgcn_s_setprio(0);                                        \
    __builtin_amdgcn_s_barrier();                                         \
  }

#define BOUNDARY(p, koff, pre) {                                          \
    __builtin_amdgcn_sched_barrier(0);                                    \
    if (pre) {                                                            \
      STAGE(p, koff);                                                     \
      __builtin_amdgcn_sched_barrier(0);                                  \
      asm volatile("s_waitcnt vmcnt(6)" ::: "memory");                    \
    } else {                                                              \
      asm volatile("s_waitcnt vmcnt(0)" ::: "memory");                    \
    }                                                                     \
    __builtin_amdgcn_s_barrier();                                         \
    __builtin_amdgcn_sched_barrier(0);                                    \
  }

__global__ __launch_bounds__(512, 2)
void gemm_k(const u16* __restrict__ A, const u16* __restrict__ Wt,
            u16* __restrict__ oQ, u16* __restrict__ oK, u16* __restrict__ oV,
            float* __restrict__ oO, const int* __restrict__ tp, int opmode)
{
  __shared__ u16 As[2][BM * BK];   // 2 x 32 KiB
  __shared__ u16 Bs[2][BN * BK];   // 2 x 16 KiB
  const int t = threadIdx.x;
  const int w = t >> 6, lane = t & 63;
  const int l16 = lane & 15, quad = lane >> 4;
  const int wr = w >> 2, wc = w & 3;               // 2M x 4N waves
  const int m0 = blockIdx.y * BM, n0 = blockIdx.x * BN;
  const u16* Bt = Wt + (size_t)(opmode == 1 ? 3 : blockIdx.z) * DM * DM;

  // ---- staging units: A 2048 units (4/thread), B 1024 units (2/thread).
  // unit u -> row u>>3, stored granule u&7 holds source granule (u&7)^(row&7).
  int uu, rr, cc;
  uu = t;        rr = uu >> 3; cc = (uu & 7) ^ (rr & 7);
  const u16* pA0 = A + (size_t)(m0 + rr) * DM + cc * 8; const int oA0 = uu * 8;
  uu = t + 512;  rr = uu >> 3; cc = (uu & 7) ^ (rr & 7);
  const u16* pA1 = A + (size_t)(m0 + rr) * DM + cc * 8; const int oA1 = uu * 8;
  uu = t + 1024; rr = uu >> 3; cc = (uu & 7) ^ (rr & 7);
  const u16* pA2 = A + (size_t)(m0 + rr) * DM + cc * 8; const int oA2 = uu * 8;
  uu = t + 1536; rr = uu >> 3; cc = (uu & 7) ^ (rr & 7);
  const u16* pA3 = A + (size_t)(m0 + rr) * DM + cc * 8; const int oA3 = uu * 8;
  uu = t;        rr = uu >> 3; cc = (uu & 7) ^ (rr & 7);
  const u16* pB0 = Bt + (size_t)(n0 + rr) * DM + cc * 8; const int oB0 = uu * 8;
  uu = t + 512;  rr = uu >> 3; cc = (uu & 7) ^ (rr & 7);
  const u16* pB1 = Bt + (size_t)(n0 + rr) * DM + cc * 8; const int oB1 = uu * 8;

  // ---- fragment read offsets (u16 units). sA = sB = l16&7 since row bases
  // are multiples of 8; XOR key invariant across mi/ni (16 = 0 mod 8).
  const int arow64 = (wr * 128 + l16) * 64;
  const int brow64 = (wc * 32 + l16) * 64;
  const int xk0 = ((quad) ^ (l16 & 7)) << 3;
  const int xk1 = ((4 + quad) ^ (l16 & 7)) << 3;

  floatx4 acc[8][2] = {};
  short8 bA, bB, bC, bD;

  // ---- prologue: tiles 0 -> buf0, 1 -> buf1; wait tile0 (6 outstanding)
  STAGE(0, 0);
  STAGE(1, BK);
  __builtin_amdgcn_sched_barrier(0);
  asm volatile("s_waitcnt vmcnt(6)" ::: "memory");
  __builtin_amdgcn_s_barrier();
  __builtin_amdgcn_sched_barrier(0);

  for (int it = 0; it < NT / 2; ++it) {
    const int koffE = it * 128 + 128;       // tile 2it+2 -> buf0
    const int koffO = it * 128 + 192;       // tile 2it+3 -> buf1
    const bool pre = (it < NT / 2 - 1);
    // tile 2it from buf0
    PHASE(0, 0, 1) PHASE(0, 1, 0) PHASE(0, 2, 0) PHASE(0, 3, 0)
    BOUNDARY(0, koffE, pre)                 // buf0 free; wait tile 2it+1
    // tile 2it+1 from buf1
    PHASE(1, 0, 1) PHASE(1, 1, 0) PHASE(1, 2, 0) PHASE(1, 3, 0)
    BOUNDARY(1, koffO, pre)                 // buf1 free; wait tile 2it+2
  }

  // ---- epilogue: per-wave 128x32 tile; m = quad*4+r, n = l16 within frag
  const int mode = (opmode == 1) ? 3 : ((int)blockIdx.z == 2 ? 2 : 0);
  const int mbase = m0 + wr * 128;
  const int nbase = n0 + wc * 32;
  if (mode == 3) {
#pragma unroll
    for (int mi = 0; mi < 8; mi++) {
      int m = mbase + mi * 16 + quad * 4;
#pragma unroll
      for (int ni = 0; ni < 2; ni++) {
        int n = nbase + ni * 16 + l16;
#pragma unroll
        for (int r = 0; r < 4; r++)
          oO[(size_t)(m + r) * DM + n] = acc[mi][ni][r];
      }
    }
  } else if (mode == 2) {
#pragma unroll
    for (int mi = 0; mi < 8; mi++) {
      int m = mbase + mi * 16 + quad * 4;
      int b = m >> 11, s = m & (S - 1);
#pragma unroll
      for (int ni = 0; ni < 2; ni++) {
        int f = nbase + ni * 16 + l16;
        int h = f >> 7, dh = f & (DH - 1);
        uint2 pk; pk.x = pack2(acc[mi][ni][0], acc[mi][ni][1]);
        pk.y = pack2(acc[mi][ni][2], acc[mi][ni][3]);
        *(uint2*)&oV[((size_t)(b * NH + h) * DH + dh) * S + s] = pk;
      }
    }
  } else {
    // RoPE fused; for Q (z==0) also fold 1/sqrt(dk)*log2(e) into the value
    u16* Out = ((int)blockIdx.z == 0) ? oQ : oK;
    const float qs = ((int)blockIdx.z == 0) ? 0.12752780f : 1.0f;
#pragma unroll
    for (int mi = 0; mi < 8; mi++) {
#pragma unroll
      for (int r = 0; r < 4; r++) {
        int m = mbase + mi * 16 + quad * 4 + r;
        int b = m >> 11, s = m & (S - 1);
        int ps = tp[s];
#pragma unroll
        for (int ni = 0; ni < 2; ni++) {
          int f = nbase + ni * 16 + l16;
          int h = f >> 7, dh = f & (DH - 1);
          float own = acc[mi][ni][r];
          float oth = __shfl_xor(own, 1, 64);
          float fr = __expf((float)(dh & ~1) * (-9.210340371976184f / 128.0f));
          float ang = (float)ps * fr;
          float sn, cs; __sincosf(ang, &sn, &cs);
          float res = (dh & 1) ? (oth * sn + own * cs) : (own * cs - oth * sn);
          Out[((size_t)(b * NH + h) * S + s) * DH + dh] = f2bf(res * qs);
        }
      }
    }
  }
}

// ---------- causal flash attention v7: 16 q/wave, fixed-base softmax, 40KB LDS ----------
// P is unpadded (16x64) with 16B-granule XOR swizzle -> Ks+Vs+P = 40960 B exactly,
// 4 blocks/CU at __launch_bounds__(256,4). Fixed-base softmax as v6.
__global__ __launch_bounds__(256, 4)
void attn_k(const u16* __restrict__ Q, const u16* __restrict__ K,
            const u16* __restrict__ Vt, u16* __restrict__ O)
{
  __shared__ u16 Ks[64 * 128];   // key-major, swizzle: unit r*16 + (c ^ (r&15))
  __shared__ u16 Vs[128 * 64];   // dh-major,  swizzle: unit r*8  + (c ^ (r&7))
  __shared__ u16 P[4][16 * 64];  // per-wave 16 q x 64 keys, 16B-XOR-swizzled
  const int t = threadIdx.x, w = t >> 6, lane = t & 63;
  const int l16 = lane & 15, quad = lane >> 4;
  const int task = blockIdx.x;
  const int bh = task & 31, b = bh >> 4, h = bh & 15;
  const int g = 31 - (task >> 5);        // big groups dispatch first (LPT)
  const int qg = g * 64;
  const int qt = qg + w * 16;
  const u16* Qb = Q + (size_t)bh * S * DH;
  const u16* Kb = K + (size_t)bh * S * DH;
  const u16* Vb = Vt + (size_t)bh * DH * S;
  u16* Pw = P[w];
  const int pxor = l16 & 7;

  const u16* pK[4]; u16* lK[4];
  const u16* pV[4]; u16* lV[4];
#pragma unroll
  for (int j = 0; j < 4; j++) {
    int kr = w * 16 + j * 4 + (lane >> 4);
    int ks = lane & 15;
    int kc = ks ^ (kr & 15);
    pK[j] = Kb + (size_t)kr * DH + kc * 8;
    lK[j] = &Ks[kr * 128 + ks * 8];
    int vr = w * 32 + j * 8 + (lane >> 3);
    int vs = lane & 7;
    int vc = vs ^ (vr & 7);
    pV[j] = Vb + (size_t)vr * S + vc * 8;
    lV[j] = &Vs[vr * 64 + vs * 8];
  }

  short8 aq[4];
#pragma unroll
  for (int kc = 0; kc < 4; kc++)
    aq[kc] = *(const short8*)&Qb[(size_t)(qt + l16) * DH + kc * 32 + quad * 8];

  floatx4 o[8] = {};
  float lsum = 0.0f;                 // per-lane partial: keys in own quad-subset
  const int kend = qg + 64;

  for (int k0 = 0; k0 < kend; k0 += 64) {
#pragma unroll
    for (int j = 0; j < 4; j++) async_cp16(pK[j] + (size_t)k0 * DH, lK[j]);
#pragma unroll
    for (int j = 0; j < 4; j++) async_cp16(pV[j] + k0, lV[j]);
    __syncthreads();

    // ---- S^T = K·Q^T : sc[hh] row = key k0+hh*16+quad*4+r, col = q = l16
    floatx4 sc[4] = {};
#pragma unroll
    for (int hh = 0; hh < 4; hh++) {
      int row = hh * 16 + l16;
#pragma unroll
      for (int kc = 0; kc < 4; kc++) {
        short8 kf = *(short8*)&Ks[row * 128 + (((kc * 4 + quad) ^ l16) << 3)];
        sc[hh] = mfma16(kf, aq[kc], sc[hh]);
      }
    }
    // ---- causal mask (only the diagonal-overlapping tile)
    if (k0 + 64 > qt) {
#pragma unroll
      for (int hh = 0; hh < 4; hh++)
#pragma unroll
        for (int r = 0; r < 4; r++) {
          int j = k0 + hh * 16 + quad * 4 + r;
          if (j > qt + l16) sc[hh][r] = -3.0e38f;
        }
    }
    // ---- direct exp2 softmax numerator; per-lane l accumulation
#pragma unroll
    for (int hh = 0; hh < 4; hh++) {
      float e0 = __builtin_amdgcn_exp2f(fminf(sc[hh][0], 44.0f));
      float e1 = __builtin_amdgcn_exp2f(fminf(sc[hh][1], 44.0f));
      float e2 = __builtin_amdgcn_exp2f(fminf(sc[hh][2], 44.0f));
      float e3 = __builtin_amdgcn_exp2f(fminf(sc[hh][3], 44.0f));
      lsum += (e0 + e1) + (e2 + e3);
      uint2 pk; pk.x = pack2(e0, e1); pk.y = pack2(e2, e3);
      // write keys hh*16+quad*4..+3 of row q=l16: 16B-unit u = 2hh + quad/2,
      // swizzled u^pxor, 8B half (quad&1)
      int su = (2 * hh + (quad >> 1)) ^ pxor;
      *(uint2*)&Pw[l16 * 64 + su * 8 + (quad & 1) * 4] = pk;
    }
    asm volatile("s_waitcnt lgkmcnt(0)" ::: "memory");
    // ---- O^T += V^T · P^T
#pragma unroll
    for (int c = 0; c < 2; c++) {
      // read keys c*32+quad*8..+7 of row l16: 16B-unit u = 4c+quad, swizzled
      short8 pf = *(short8*)&Pw[l16 * 64 + (((4 * c + quad) ^ pxor) << 3)];
#pragma unroll
      for (int t8 = 0; t8 < 8; t8++) {
        int row = t8 * 16 + l16;
        short8 av = *(short8*)&Vs[row * 64 + (((c * 4 + quad) ^ (l16 & 7)) << 3)];
        o[t8] = mfma16(av, pf, o[t8]);
      }
    }
    __syncthreads();
  }

  // ---- epilogue: reduce l across quads ONCE, then scale and store
  float l = lsum + __shfl_xor(lsum, 16, 64);
  l += __shfl_xor(l, 32, 64);
  float inv = __builtin_amdgcn_rcpf(l);
#pragma unroll
  for (int t8 = 0; t8 < 8; t8++) {
    uint2 pa;
    pa.x = pack2(o[t8][0] * inv, o[t8][1] * inv);
    pa.y = pack2(o[t8][2] * inv, o[t8][3] * inv);
    *(uint2*)&O[((size_t)(b * S + qt + l16)) * DM + h * DH + t8 * 16 + quad * 4] = pa;
  }
}

extern "C" void kernel_launch(void* const* d_in, const int* in_sizes, int n_in,
                              void* d_out, int out_size, void* d_ws, size_t ws_size,
                              hipStream_t stream) {
  const float* x  = (const float*)d_in[0];
  const float* Wq = (const float*)d_in[1];
  const float* Wk = (const float*)d_in[2];
  const float* Wv = (const float*)d_in[3];
  const float* Wo = (const float*)d_in[4];
  const int*   tp = (const int*)d_in[5];

  char* ws = (char*)d_ws;
  u16* Wt = (u16*)ws;
  u16* xb = (u16*)(ws + 33554432);
  u16* Qb = (u16*)(ws + 50331648);
  u16* Kb = (u16*)(ws + 67108864);
  u16* Vb = (u16*)(ws + 83886080);
  u16* Ob = (u16*)(ws + 100663296);

  conv_x_k<<<8192, 256, 0, stream>>>(x, xb);
  conv_w_k<<<dim3(64, 64, 4), 256, 0, stream>>>(Wq, Wk, Wv, Wo, Wt);
  gemm_k<<<dim3(DM / BN, 4096 / BM, 3), 512, 0, stream>>>(xb, Wt, Qb, Kb, Vb,
                                                          nullptr, tp, 0);
  attn_k<<<1024, 256, 0, stream>>>(Qb, Kb, Vb, Ob);
  gemm_k<<<dim3(DM / BN, 4096 / BM, 1), 512, 0, stream>>>(Ob, Wt, nullptr, nullptr,
                                                          nullptr, (float*)d_out, tp, 1);
}

// Round 2
// 380.496 us; speedup vs baseline: 1.0074x; 1.0074x over previous
//
#include <hip/hip_runtime.h>
#include <hip/hip_bf16.h>

#define S 2048
#define DM 2048
#define NH 16
#define DH 128

typedef __attribute__((ext_vector_type(8))) short short8;
typedef __attribute__((ext_vector_type(4))) float floatx4;
typedef unsigned short u16;
typedef unsigned int u32;

__device__ __forceinline__ u16 f2bf(float f) {
  union { float f; u32 u; } v; v.f = f;
  u32 r = v.u + 0x7fffu + ((v.u >> 16) & 1u);
  return (u16)(r >> 16);
}
// HW packed round-to-nearest-even f32x2 -> bf16x2 (v_cvt_pk_bf16_f32)
__device__ __forceinline__ u32 pack2(float lo, float hi) {
  float2 f; f.x = lo; f.y = hi;
  __hip_bfloat162 h = __float22bfloat162_rn(f);
  union { __hip_bfloat162 h; u32 u; } c; c.h = h;
  return c.u;
}

__device__ __forceinline__ floatx4 mfma16(short8 a, short8 b, floatx4 c) {
  return __builtin_amdgcn_mfma_f32_16x16x32_bf16(a, b, c, 0, 0, 0);
}

// async global -> LDS, 16B per lane. LDS dest = wave-uniform base + lane*16.
__device__ __forceinline__ void async_cp16(const u16* g, u16* l) {
  __builtin_amdgcn_global_load_lds(
      (const __attribute__((address_space(1))) void*)g,
      (__attribute__((address_space(3))) void*)l, 16, 0, 0);
}

// ---------- convert x (fp32 -> bf16), 4 elems/thread ----------
__global__ void conv_x_k(const float* __restrict__ x, u16* __restrict__ xb) {
  int gid = blockIdx.x * 256 + threadIdx.x;
  float4 v = ((const float4*)x)[gid];
  uint2 p; p.x = pack2(v.x, v.y); p.y = pack2(v.z, v.w);
  ((uint2*)xb)[gid] = p;
}

// ---------- transpose+convert weights: Wt[n*2048+k] = bf16(W[k*2048+n]) ----------
__global__ void conv_w_k(const float* __restrict__ W0, const float* __restrict__ W1,
                         const float* __restrict__ W2, const float* __restrict__ W3,
                         u16* __restrict__ out) {
  __shared__ float tile[32][33];
  const float* W = blockIdx.z == 0 ? W0 : blockIdx.z == 1 ? W1 : blockIdx.z == 2 ? W2 : W3;
  u16* O = out + (size_t)blockIdx.z * DM * DM;
  int tx = threadIdx.x & 31, ty = threadIdx.x >> 5;
  int k0 = blockIdx.y * 32, n0 = blockIdx.x * 32;
#pragma unroll
  for (int j = 0; j < 4; j++)
    tile[ty + j * 8][tx] = W[(size_t)(k0 + ty + j * 8) * DM + n0 + tx];
  __syncthreads();
#pragma unroll
  for (int j = 0; j < 4; j++)
    O[(size_t)(n0 + ty + j * 8) * DM + k0 + tx] = f2bf(tile[tx][ty + j * 8]);
}

// ---------- 256x128 bf16 MFMA GEMM, 2-phase/K-tile schedule (T2+T3+T4+T5) ----------
// 8 waves as 4M x 2N -> per-wave 64x64 (4 m-frags x 4 n-frags): 32 MFMA vs
// 16 ds_read_b128 per K-tile per wave, split into 2 phases of 16 MFMA each
// (phase0: 12 reads incl. all B-frags; phase1: 4 A-reads, B held in regs).
// Double-buffered LDS (96 KiB), counted vmcnt(6): tile T+2 staged into the
// just-freed buffer at each K-tile boundary; vmcnt never drains to 0 in the
// main loop. LDS swizzle: granule g' = g ^ (row&7), linear global_load_lds
// dest + inverse-swizzled global src + swizzled ds_read (rule #21).
#define BM 256
#define BN 128
#define BK 64
#define NT (DM / BK)   // 32 K-tiles, 16 iterations

#define STAGE(p, koff) do {                       \
    async_cp16(pA0 + (koff), &As[p][oA0]);        \
    async_cp16(pA1 + (koff), &As[p][oA1]);        \
    async_cp16(pA2 + (koff), &As[p][oA2]);        \
    async_cp16(pA3 + (koff), &As[p][oA3]);        \
    async_cp16(pB0 + (koff), &Bs[p][oB0]);        \
    async_cp16(pB1 + (koff), &Bs[p][oB1]);        \
  } while (0)

#define PHASE0(p) {                                                       \
    short8 a0k0 = *(const short8*)&As[p][abase + xk0];                    \
    short8 a0k1 = *(const short8*)&As[p][abase + xk1];                    \
    short8 a1k0 = *(const short8*)&As[p][abase + 1024 + xk0];             \
    short8 a1k1 = *(const short8*)&As[p][abase + 1024 + xk1];             \
    b00 = *(const short8*)&Bs[p][bbase + xk0];                            \
    b01 = *(const short8*)&Bs[p][bbase + xk1];                            \
    b10 = *(const short8*)&Bs[p][bbase + 1024 + xk0];                     \
    b11 = *(const short8*)&Bs[p][bbase + 1024 + xk1];                     \
    b20 = *(const short8*)&Bs[p][bbase + 2048 + xk0];                     \
    b21 = *(const short8*)&Bs[p][bbase + 2048 + xk1];                     \
    b30 = *(const short8*)&Bs[p][bbase + 3072 + xk0];                     \
    b31 = *(const short8*)&Bs[p][bbase + 3072 + xk1];                     \
    __builtin_amdgcn_s_barrier();                                         \
    asm volatile("s_waitcnt lgkmcnt(0)" ::: "memory");                    \
    __builtin_amdgcn_sched_barrier(0);                                    \
    __builtin_amdgcn_s_setprio(1);                                        \
    acc[0][0] = mfma16(a0k0, b00, acc[0][0]);                             \
    acc[0][1] = mfma16(a0k0, b10, acc[0][1]);                             \
    acc[0][2] = mfma16(a0k0, b20, acc[0][2]);                             \
    acc[0][3] = mfma16(a0k0, b30, acc[0][3]);                             \
    acc[1][0] = mfma16(a1k0, b00, acc[1][0]);                             \
    acc[1][1] = mfma16(a1k0, b10, acc[1][1]);                             \
    acc[1][2] = mfma16(a1k0, b20, acc[1][2]);                             \
    acc[1][3] = mfma16(a1k0, b30, acc[1][3]);                             \
    acc[0][0] = mfma16(a0k1, b01, acc[0][0]);                             \
    acc[0][1] = mfma16(a0k1, b11, acc[0][1]);                             \
    acc[0][2] = mfma16(a0k1, b21, acc[0][2]);                             \
    acc[0][3] = mfma16(a0k1, b31, acc[0][3]);                             \
    acc[1][0] = mfma16(a1k1, b01, acc[1][0]);                             \
    acc[1][1] = mfma16(a1k1, b11, acc[1][1]);                             \
    acc[1][2] = mfma16(a1k1, b21, acc[1][2]);                             \
    acc[1][3] = mfma16(a1k1, b31, acc[1][3]);                             \
    __builtin_amdgcn_s_setprio(0);                                        \
    __builtin_amdgcn_s_barrier();                                         \
  }

#define PHASE1(p) {                                                       \
    short8 a2k0 = *(const short8*)&As[p][abase + 2048 + xk0];             \
    short8 a2k1 = *(const short8*)&As[p][abase + 2048 + xk1];             \
    short8 a3k0 = *(const short8*)&As[p][abase + 3072 + xk0];             \
    short8 a3k1 = *(const short8*)&As[p][abase + 3072 + xk1];             \
    __builtin_amdgcn_s_barrier();                                         \
    asm volatile("s_waitcnt lgkmcnt(0)" ::: "memory");                    \
    __builtin_amdgcn_sched_barrier(0);                                    \
    __builtin_amdgcn_s_setprio(1);                                        \
    acc[2][0] = mfma16(a2k0, b00, acc[2][0]);                             \
    acc[2][1] = mfma16(a2k0, b10, acc[2][1]);                             \
    acc[2][2] = mfma16(a2k0, b20, acc[2][2]);                             \
    acc[2][3] = mfma16(a2k0, b30, acc[2][3]);                             \
    acc[3][0] = mfma16(a3k0, b00, acc[3][0]);                             \
    acc[3][1] = mfma16(a3k0, b10, acc[3][1]);                             \
    acc[3][2] = mfma16(a3k0, b20, acc[3][2]);                             \
    acc[3][3] = mfma16(a3k0, b30, acc[3][3]);                             \
    acc[2][0] = mfma16(a2k1, b01, acc[2][0]);                             \
    acc[2][1] = mfma16(a2k1, b11, acc[2][1]);                             \
    acc[2][2] = mfma16(a2k1, b21, acc[2][2]);                             \
    acc[2][3] = mfma16(a2k1, b31, acc[2][3]);                             \
    acc[3][0] = mfma16(a3k1, b01, acc[3][0]);                             \
    acc[3][1] = mfma16(a3k1, b11, acc[3][1]);                             \
    acc[3][2] = mfma16(a3k1, b21, acc[3][2]);                             \
    acc[3][3] = mfma16(a3k1, b31, acc[3][3]);                             \
    __builtin_amdgcn_s_setprio(0);                                        \
    __builtin_amdgcn_s_barrier();                                         \
  }

#define BOUNDARY(p, koff, pre) {                                          \
    __builtin_amdgcn_sched_barrier(0);                                    \
    if (pre) {                                                            \
      STAGE(p, koff);                                                     \
      __builtin_amdgcn_sched_barrier(0);                                  \
      asm volatile("s_waitcnt vmcnt(6)" ::: "memory");                    \
    } else {                                                              \
      asm volatile("s_waitcnt vmcnt(0)" ::: "memory");                    \
    }                                                                     \
    __builtin_amdgcn_s_barrier();                                         \
    __builtin_amdgcn_sched_barrier(0);                                    \
  }

__global__ __launch_bounds__(512, 2)
void gemm_k(const u16* __restrict__ A, const u16* __restrict__ Wt,
            u16* __restrict__ oQ, u16* __restrict__ oK, u16* __restrict__ oV,
            float* __restrict__ oO, const int* __restrict__ tp, int opmode)
{
  __shared__ u16 As[2][BM * BK];   // 2 x 32 KiB
  __shared__ u16 Bs[2][BN * BK];   // 2 x 16 KiB
  const int t = threadIdx.x;
  const int w = t >> 6, lane = t & 63;
  const int l16 = lane & 15, quad = lane >> 4;
  const int wr = w >> 1, wc = w & 1;               // 4M x 2N waves, 64x64 each
  const int m0 = blockIdx.y * BM, n0 = blockIdx.x * BN;
  const u16* Bt = Wt + (size_t)(opmode == 1 ? 3 : blockIdx.z) * DM * DM;

  // ---- staging units: A 2048 units (4/thread), B 1024 units (2/thread).
  // unit u -> row u>>3, stored granule u&7 holds source granule (u&7)^(row&7).
  int uu, rr, cc;
  uu = t;        rr = uu >> 3; cc = (uu & 7) ^ (rr & 7);
  const u16* pA0 = A + (size_t)(m0 + rr) * DM + cc * 8; const int oA0 = uu * 8;
  uu = t + 512;  rr = uu >> 3; cc = (uu & 7) ^ (rr & 7);
  const u16* pA1 = A + (size_t)(m0 + rr) * DM + cc * 8; const int oA1 = uu * 8;
  uu = t + 1024; rr = uu >> 3; cc = (uu & 7) ^ (rr & 7);
  const u16* pA2 = A + (size_t)(m0 + rr) * DM + cc * 8; const int oA2 = uu * 8;
  uu = t + 1536; rr = uu >> 3; cc = (uu & 7) ^ (rr & 7);
  const u16* pA3 = A + (size_t)(m0 + rr) * DM + cc * 8; const int oA3 = uu * 8;
  uu = t;        rr = uu >> 3; cc = (uu & 7) ^ (rr & 7);
  const u16* pB0 = Bt + (size_t)(n0 + rr) * DM + cc * 8; const int oB0 = uu * 8;
  uu = t + 512;  rr = uu >> 3; cc = (uu & 7) ^ (rr & 7);
  const u16* pB1 = Bt + (size_t)(n0 + rr) * DM + cc * 8; const int oB1 = uu * 8;

  // ---- fragment read offsets (u16 units). row&7 == l16&7 (bases mult. of 8)
  const int abase = (wr * 64 + l16) * 64;
  const int bbase = (wc * 64 + l16) * 64;
  const int xk0 = ((quad) ^ (l16 & 7)) << 3;
  const int xk1 = ((4 + quad) ^ (l16 & 7)) << 3;

  floatx4 acc[4][4] = {};
  short8 b00, b01, b10, b11, b20, b21, b30, b31;

  // ---- prologue: tiles 0 -> buf0, 1 -> buf1; wait tile0 (6 outstanding)
  STAGE(0, 0);
  STAGE(1, BK);
  __builtin_amdgcn_sched_barrier(0);
  asm volatile("s_waitcnt vmcnt(6)" ::: "memory");
  __builtin_amdgcn_s_barrier();
  __builtin_amdgcn_sched_barrier(0);

  for (int it = 0; it < NT / 2; ++it) {
    const int koffE = it * 128 + 128;       // tile 2it+2 -> buf0
    const int koffO = it * 128 + 192;       // tile 2it+3 -> buf1
    const bool pre = (it < NT / 2 - 1);
    // tile 2it from buf0
    PHASE0(0) PHASE1(0)
    BOUNDARY(0, koffE, pre)                 // buf0 free; wait tile 2it+1
    // tile 2it+1 from buf1
    PHASE0(1) PHASE1(1)
    BOUNDARY(1, koffO, pre)                 // buf1 free; wait tile 2it+2
  }

  // ---- epilogue: per-wave 64x64 tile; m = quad*4+r, n = l16 within frag
  const int mode = (opmode == 1) ? 3 : ((int)blockIdx.z == 2 ? 2 : 0);
  const int mbase = m0 + wr * 64;
  const int nbase = n0 + wc * 64;
  if (mode == 3) {
#pragma unroll
    for (int mi = 0; mi < 4; mi++) {
      int m = mbase + mi * 16 + quad * 4;
#pragma unroll
      for (int ni = 0; ni < 4; ni++) {
        int n = nbase + ni * 16 + l16;
#pragma unroll
        for (int r = 0; r < 4; r++)
          oO[(size_t)(m + r) * DM + n] = acc[mi][ni][r];
      }
    }
  } else if (mode == 2) {
#pragma unroll
    for (int mi = 0; mi < 4; mi++) {
      int m = mbase + mi * 16 + quad * 4;
      int b = m >> 11, s = m & (S - 1);
#pragma unroll
      for (int ni = 0; ni < 4; ni++) {
        int f = nbase + ni * 16 + l16;
        int h = f >> 7, dh = f & (DH - 1);
        uint2 pk; pk.x = pack2(acc[mi][ni][0], acc[mi][ni][1]);
        pk.y = pack2(acc[mi][ni][2], acc[mi][ni][3]);
        *(uint2*)&oV[((size_t)(b * NH + h) * DH + dh) * S + s] = pk;
      }
    }
  } else {
    // RoPE fused; for Q (z==0) also fold 1/sqrt(dk)*log2(e) into the value
    u16* Out = ((int)blockIdx.z == 0) ? oQ : oK;
    const float qs = ((int)blockIdx.z == 0) ? 0.12752780f : 1.0f;
#pragma unroll
    for (int mi = 0; mi < 4; mi++) {
#pragma unroll
      for (int r = 0; r < 4; r++) {
        int m = mbase + mi * 16 + quad * 4 + r;
        int b = m >> 11, s = m & (S - 1);
        int ps = tp[s];
#pragma unroll
        for (int ni = 0; ni < 4; ni++) {
          int f = nbase + ni * 16 + l16;
          int h = f >> 7, dh = f & (DH - 1);
          float own = acc[mi][ni][r];
          float oth = __shfl_xor(own, 1, 64);
          float fr = __expf((float)(dh & ~1) * (-9.210340371976184f / 128.0f));
          float ang = (float)ps * fr;
          float sn, cs; __sincosf(ang, &sn, &cs);
          float res = (dh & 1) ? (oth * sn + own * cs) : (own * cs - oth * sn);
          Out[((size_t)(b * NH + h) * S + s) * DH + dh] = f2bf(res * qs);
        }
      }
    }
  }
}

// ---------- causal flash attention v7: 16 q/wave, fixed-base softmax, 40KB LDS ----------
// P is unpadded (16x64) with 16B-granule XOR swizzle -> Ks+Vs+P = 40960 B exactly,
// 4 blocks/CU at __launch_bounds__(256,4). Fixed-base softmax as v6.
__global__ __launch_bounds__(256, 4)
void attn_k(const u16* __restrict__ Q, const u16* __restrict__ K,
            const u16* __restrict__ Vt, u16* __restrict__ O)
{
  __shared__ u16 Ks[64 * 128];   // key-major, swizzle: unit r*16 + (c ^ (r&15))
  __shared__ u16 Vs[128 * 64];   // dh-major,  swizzle: unit r*8  + (c ^ (r&7))
  __shared__ u16 P[4][16 * 64];  // per-wave 16 q x 64 keys, 16B-XOR-swizzled
  const int t = threadIdx.x, w = t >> 6, lane = t & 63;
  const int l16 = lane & 15, quad = lane >> 4;
  const int task = blockIdx.x;
  const int bh = task & 31, b = bh >> 4, h = bh & 15;
  const int g = 31 - (task >> 5);        // big groups dispatch first (LPT)
  const int qg = g * 64;
  const int qt = qg + w * 16;
  const u16* Qb = Q + (size_t)bh * S * DH;
  const u16* Kb = K + (size_t)bh * S * DH;
  const u16* Vb = Vt + (size_t)bh * DH * S;
  u16* Pw = P[w];
  const int pxor = l16 & 7;

  const u16* pK[4]; u16* lK[4];
  const u16* pV[4]; u16* lV[4];
#pragma unroll
  for (int j = 0; j < 4; j++) {
    int kr = w * 16 + j * 4 + (lane >> 4);
    int ks = lane & 15;
    int kc = ks ^ (kr & 15);
    pK[j] = Kb + (size_t)kr * DH + kc * 8;
    lK[j] = &Ks[kr * 128 + ks * 8];
    int vr = w * 32 + j * 8 + (lane >> 3);
    int vs = lane & 7;
    int vc = vs ^ (vr & 7);
    pV[j] = Vb + (size_t)vr * S + vc * 8;
    lV[j] = &Vs[vr * 64 + vs * 8];
  }

  short8 aq[4];
#pragma unroll
  for (int kc = 0; kc < 4; kc++)
    aq[kc] = *(const short8*)&Qb[(size_t)(qt + l16) * DH + kc * 32 + quad * 8];

  floatx4 o[8] = {};
  float lsum = 0.0f;                 // per-lane partial: keys in own quad-subset
  const int kend = qg + 64;

  for (int k0 = 0; k0 < kend; k0 += 64) {
#pragma unroll
    for (int j = 0; j < 4; j++) async_cp16(pK[j] + (size_t)k0 * DH, lK[j]);
#pragma unroll
    for (int j = 0; j < 4; j++) async_cp16(pV[j] + k0, lV[j]);
    __syncthreads();

    // ---- S^T = K·Q^T : sc[hh] row = key k0+hh*16+quad*4+r, col = q = l16
    floatx4 sc[4] = {};
#pragma unroll
    for (int hh = 0; hh < 4; hh++) {
      int row = hh * 16 + l16;
#pragma unroll
      for (int kc = 0; kc < 4; kc++) {
        short8 kf = *(short8*)&Ks[row * 128 + (((kc * 4 + quad) ^ l16) << 3)];
        sc[hh] = mfma16(kf, aq[kc], sc[hh]);
      }
    }
    // ---- causal mask (only the diagonal-overlapping tile)
    if (k0 + 64 > qt) {
#pragma unroll
      for (int hh = 0; hh < 4; hh++)
#pragma unroll
        for (int r = 0; r < 4; r++) {
          int j = k0 + hh * 16 + quad * 4 + r;
          if (j > qt + l16) sc[hh][r] = -3.0e38f;
        }
    }
    // ---- direct exp2 softmax numerator; per-lane l accumulation
#pragma unroll
    for (int hh = 0; hh < 4; hh++) {
      float e0 = __builtin_amdgcn_exp2f(fminf(sc[hh][0], 44.0f));
      float e1 = __builtin_amdgcn_exp2f(fminf(sc[hh][1], 44.0f));
      float e2 = __builtin_amdgcn_exp2f(fminf(sc[hh][2], 44.0f));
      float e3 = __builtin_amdgcn_exp2f(fminf(sc[hh][3], 44.0f));
      lsum += (e0 + e1) + (e2 + e3);
      uint2 pk; pk.x = pack2(e0, e1); pk.y = pack2(e2, e3);
      // write keys hh*16+quad*4..+3 of row q=l16: 16B-unit u = 2hh + quad/2,
      // swizzled u^pxor, 8B half (quad&1)
      int su = (2 * hh + (quad >> 1)) ^ pxor;
      *(uint2*)&Pw[l16 * 64 + su * 8 + (quad & 1) * 4] = pk;
    }
    asm volatile("s_waitcnt lgkmcnt(0)" ::: "memory");
    // ---- O^T += V^T · P^T
#pragma unroll
    for (int c = 0; c < 2; c++) {
      // read keys c*32+quad*8..+7 of row l16: 16B-unit u = 4c+quad, swizzled
      short8 pf = *(short8*)&Pw[l16 * 64 + (((4 * c + quad) ^ pxor) << 3)];
#pragma unroll
      for (int t8 = 0; t8 < 8; t8++) {
        int row = t8 * 16 + l16;
        short8 av = *(short8*)&Vs[row * 64 + (((c * 4 + quad) ^ (l16 & 7)) << 3)];
        o[t8] = mfma16(av, pf, o[t8]);
      }
    }
    __syncthreads();
  }

  // ---- epilogue: reduce l across quads ONCE, then scale and store
  float l = lsum + __shfl_xor(lsum, 16, 64);
  l += __shfl_xor(l, 32, 64);
  float inv = __builtin_amdgcn_rcpf(l);
#pragma unroll
  for (int t8 = 0; t8 < 8; t8++) {
    uint2 pa;
    pa.x = pack2(o[t8][0] * inv, o[t8][1] * inv);
    pa.y = pack2(o[t8][2] * inv, o[t8][3] * inv);
    *(uint2*)&O[((size_t)(b * S + qt + l16)) * DM + h * DH + t8 * 16 + quad * 4] = pa;
  }
}

extern "C" void kernel_launch(void* const* d_in, const int* in_sizes, int n_in,
                              void* d_out, int out_size, void* d_ws, size_t ws_size,
                              hipStream_t stream) {
  const float* x  = (const float*)d_in[0];
  const float* Wq = (const float*)d_in[1];
  const float* Wk = (const float*)d_in[2];
  const float* Wv = (const float*)d_in[3];
  const float* Wo = (const float*)d_in[4];
  const int*   tp = (const int*)d_in[5];

  char* ws = (char*)d_ws;
  u16* Wt = (u16*)ws;
  u16* xb = (u16*)(ws + 33554432);
  u16* Qb = (u16*)(ws + 50331648);
  u16* Kb = (u16*)(ws + 67108864);
  u16* Vb = (u16*)(ws + 83886080);
  u16* Ob = (u16*)(ws + 100663296);

  conv_x_k<<<8192, 256, 0, stream>>>(x, xb);
  conv_w_k<<<dim3(64, 64, 4), 256, 0, stream>>>(Wq, Wk, Wv, Wo, Wt);
  gemm_k<<<dim3(DM / BN, 4096 / BM, 3), 512, 0, stream>>>(xb, Wt, Qb, Kb, Vb,
                                                          nullptr, tp, 0);
  attn_k<<<1024, 256, 0, stream>>>(Qb, Kb, Vb, Ob);
  gemm_k<<<dim3(DM / BN, 4096 / BM, 1), 512, 0, stream>>>(Ob, Wt, nullptr, nullptr,
                                                          nullptr, (float*)d_out, tp, 1);
}